// Round 1
// baseline (207.851 us; speedup 1.0000x reference)
//
#include <hip/hip_runtime.h>

#define BATCH 2
#define L_SEQ 2048
#define DI 2048
#define NROW (BATCH * L_SEQ)   // 4096
#define E_DIM 96
#define RNK 64                 // DT_RANK
#define NST 16                 // D_STATE
#define NCH 64                 // chunks
#define CL 32                  // chunk length (NCH*CL == L_SEQ)
#define SPLITK 16              // K1 split-K factor
#define KSL (DI / SPLITK)      // 128 k per split

// ---------------- workspace layout (floats) ----------------
// xdbl  : [NROW][96]                              393216
// partials : [SPLITK][NROW][96]   6291456  (K1 -> reduce, then dead)
//   hloc   : [BATCH][NCH][DI][16] 4194304  (overlays partials; C -> S2)
//   dsum   : [BATCH][NCH][DI]      262144  (overlays partials; C -> S2)
// hent  : [BATCH][NCH][DI][16]    4194304  (S2 -> S3), after partials
#define WS_XDBL 0
#define WS_PART 393216
#define WS_HLOC 393216
#define WS_DSUM (393216 + 4194304)
#define WS_HENT (393216 + 6291456)

__device__ __forceinline__ float softplusf(float z) {
    return fmaxf(z, 0.f) + __logf(1.f + __expf(-fabsf(z)));
}

// async global->LDS, 16B per lane; lds base must be wave-uniform
__device__ __forceinline__ void glds16(const float* g, float* l) {
    __builtin_amdgcn_global_load_lds((const __attribute__((address_space(1))) void*)g,
                                     (__attribute__((address_space(3))) void*)l, 16, 0, 0);
}

// ===== K1a: partial[s] = x[:, ksl] @ W^T slice =====
// 256 threads, tile M=64 x N=96, k-step 32, KSL=128. grid (64, 16).
__global__ __launch_bounds__(256) void gemm_xproj_part(const float* __restrict__ x,
                                                       const float* __restrict__ Wx,
                                                       float* __restrict__ part) {
    __shared__ float xs[32][68];    // [k][row], pitch 272B (16B aligned)
    __shared__ float wsh[32][100];  // [k][e],  pitch 400B (16B aligned)
    const int tid = threadIdx.x;
    const int r0 = blockIdx.x * 64;
    const int kbase0 = blockIdx.y * KSL;
    const int rg = tid >> 4;   // 16 groups of 4 rows
    const int cg = tid & 15;   // 16 groups of 6 cols

    float acc[4][6];
#pragma unroll
    for (int i = 0; i < 4; i++)
#pragma unroll
        for (int j = 0; j < 6; j++) acc[i][j] = 0.f;

    for (int kt = 0; kt < KSL / 32; kt++) {
        const int kb = kbase0 + kt * 32;
#pragma unroll
        for (int rep = 0; rep < 2; rep++) {
            int i = rep * 256 + tid;   // 0..511
            int row = i >> 3;          // 0..63
            int kq = i & 7;
            float4 v = *(const float4*)&x[(long)(r0 + row) * DI + kb + kq * 4];
            xs[kq * 4 + 0][row] = v.x;
            xs[kq * 4 + 1][row] = v.y;
            xs[kq * 4 + 2][row] = v.z;
            xs[kq * 4 + 3][row] = v.w;
        }
#pragma unroll
        for (int rep = 0; rep < 3; rep++) {
            int i = rep * 256 + tid;   // 0..767
            int e = i >> 3;            // 0..95
            int kq = i & 7;
            float4 v = *(const float4*)&Wx[(long)e * DI + kb + kq * 4];
            wsh[kq * 4 + 0][e] = v.x;
            wsh[kq * 4 + 1][e] = v.y;
            wsh[kq * 4 + 2][e] = v.z;
            wsh[kq * 4 + 3][e] = v.w;
        }
        __syncthreads();
#pragma unroll 8
        for (int k = 0; k < 32; k++) {
            float xr[4], wr[6];
#pragma unroll
            for (int i = 0; i < 4; i++) xr[i] = xs[k][rg * 4 + i];
#pragma unroll
            for (int j = 0; j < 6; j++) wr[j] = wsh[k][cg * 6 + j];
#pragma unroll
            for (int i = 0; i < 4; i++)
#pragma unroll
                for (int j = 0; j < 6; j++) acc[i][j] = fmaf(xr[i], wr[j], acc[i][j]);
        }
        __syncthreads();
    }
    const long sbase = (long)blockIdx.y * NROW * E_DIM;
#pragma unroll
    for (int i = 0; i < 4; i++) {
        long rowb = sbase + (long)(r0 + rg * 4 + i) * E_DIM + cg * 6;
#pragma unroll
        for (int j = 0; j < 6; j++) part[rowb + j] = acc[i][j];
    }
}

// ===== K1b: xdbl = sum over splits (float4-vectorized) =====
__global__ __launch_bounds__(256) void xproj_reduce(const float* __restrict__ part,
                                                    float* __restrict__ xdbl) {
    const int i4 = blockIdx.x * 256 + threadIdx.x;   // 98304 float4 outputs
    const float4* p4 = (const float4*)part;
    float4 s = p4[i4];
#pragma unroll
    for (int sp = 1; sp < SPLITK; sp++) {
        float4 v = p4[(long)sp * (NROW * E_DIM / 4) + i4];
        s.x += v.x; s.y += v.y; s.z += v.z; s.w += v.w;
    }
    ((float4*)xdbl)[i4] = s;
}

// ===== C: fused delta-GEMM + chunk-local scan =====
// grid (DI/256, NCH, BATCH), 256 threads. Per block: 32 l (one chunk) x 256 d.
// Phase 1: delta tile = softplus(dlt @ Wdt^T + b) via LDS GEMM (K=64 in 2 steps).
// Phase 2: chunk-local h recurrence, pure LDS (x tile pre-staged via global_load_lds).
#define PW 260   // wt pitch (floats), 1040B rows (16B aligned)
#define PD 36    // dlb pitch (floats), 144B rows (16B aligned)
__global__ __launch_bounds__(256, 2) void gemm_dt_scan(const float* __restrict__ x,
                                                       const float* __restrict__ xdbl,
                                                       const float* __restrict__ Wdt,
                                                       const float* __restrict__ b_dt,
                                                       const float* __restrict__ A_log,
                                                       float* __restrict__ delta,
                                                       float* __restrict__ hloc,
                                                       float* __restrict__ dsumb) {
    __shared__ float xsh[CL * 256];                     // 32 KB x tile [l][d]
    __shared__ float region[32 * PW + 32 * PD];         // GEMM staging, then delta tile
    __shared__ float bsm[CL * NST];                     // 2 KB B tile
    float* wt  = region;                 // [32][PW]  Wdt staging [k][col]
    float* dlb = region + 32 * PW;       // [32][PD]  dlt staging [k][row]
    float* dtt = region;                 // [32][256] delta tile (overlay, after GEMM)

    const int tid = threadIdx.x;
    const int d0 = blockIdx.x * 256;
    const int c = blockIdx.y;
    const int b = blockIdx.z;
    const int row0 = b * L_SEQ + c * CL;
    const int wv = tid >> 6, ln = tid & 63;

    // async-stage x tile: lands during GEMM; first barrier drains vmcnt
#pragma unroll
    for (int r8 = 0; r8 < 8; r8++) {
        int r = wv * 8 + r8;                            // wave-uniform
        glds16(&x[(long)(row0 + r) * DI + d0 + ln * 4], &xsh[r * 256]);
    }
    // stage B tile (rows row0..row0+31, xdbl cols 64..79)
    if (tid < 128) {
        int r = tid >> 2, q = tid & 3;
        ((float4*)bsm)[tid] = *(const float4*)&xdbl[(long)(row0 + r) * E_DIM + 64 + q * 4];
    }

    const int rg = tid >> 6;   // 4 groups of 8 rows
    const int cg = tid & 63;   // 64 groups of 4 cols
    float acc[8][4];
#pragma unroll
    for (int i = 0; i < 8; i++)
#pragma unroll
        for (int j = 0; j < 4; j++) acc[i][j] = 0.f;

    for (int kt = 0; kt < 2; kt++) {
        const int kb = kt * 32;
        // Wdt tile: 256 cols x 32 k = 2048 float4, 8/thread
#pragma unroll
        for (int rep = 0; rep < 8; rep++) {
            int i = rep * 256 + tid;
            int col = i >> 3, kq = i & 7;
            float4 v = *(const float4*)&Wdt[(long)(d0 + col) * RNK + kb + kq * 4];
            wt[(kq * 4 + 0) * PW + col] = v.x;
            wt[(kq * 4 + 1) * PW + col] = v.y;
            wt[(kq * 4 + 2) * PW + col] = v.z;
            wt[(kq * 4 + 3) * PW + col] = v.w;
        }
        // dlt tile: 32 rows x 32 k = 256 float4, 1/thread
        {
            int r = tid >> 3, kq = tid & 7;
            float4 v = *(const float4*)&xdbl[(long)(row0 + r) * E_DIM + kb + kq * 4];
            dlb[(kq * 4 + 0) * PD + r] = v.x;
            dlb[(kq * 4 + 1) * PD + r] = v.y;
            dlb[(kq * 4 + 2) * PD + r] = v.z;
            dlb[(kq * 4 + 3) * PD + r] = v.w;
        }
        __syncthreads();
#pragma unroll 8
        for (int k = 0; k < 32; k++) {
            float4 xa = *(const float4*)&dlb[k * PD + rg * 8];       // broadcast
            float4 xb = *(const float4*)&dlb[k * PD + rg * 8 + 4];   // broadcast
            float4 wv4 = *(const float4*)&wt[k * PW + cg * 4];       // 16B-stride
            float xr[8] = {xa.x, xa.y, xa.z, xa.w, xb.x, xb.y, xb.z, xb.w};
            float wr[4] = {wv4.x, wv4.y, wv4.z, wv4.w};
#pragma unroll
            for (int i = 0; i < 8; i++)
#pragma unroll
                for (int j = 0; j < 4; j++) acc[i][j] = fmaf(xr[i], wr[j], acc[i][j]);
        }
        __syncthreads();
    }

    // epilogue: bias + softplus -> global delta + LDS delta tile (overlay is safe now)
    float4 bb = *(const float4*)&b_dt[d0 + cg * 4];
#pragma unroll
    for (int i = 0; i < 8; i++) {
        int r = rg * 8 + i;
        float4 o;
        o.x = softplusf(acc[i][0] + bb.x);
        o.y = softplusf(acc[i][1] + bb.y);
        o.z = softplusf(acc[i][2] + bb.z);
        o.w = softplusf(acc[i][3] + bb.w);
        *(float4*)&delta[(long)(row0 + r) * DI + d0 + cg * 4] = o;
        *(float4*)&dtt[r * 256 + cg * 4] = o;
    }

    // scan setup (A loads overlap the barrier)
    const int d = d0 + tid;
    float A[16];
#pragma unroll
    for (int q = 0; q < 4; q++) {
        float4 v = *(const float4*)&A_log[(long)d * NST + q * 4];
        A[q * 4 + 0] = -__expf(v.x);
        A[q * 4 + 1] = -__expf(v.y);
        A[q * 4 + 2] = -__expf(v.z);
        A[q * 4 + 3] = -__expf(v.w);
    }
    __syncthreads();

    float h[16];
#pragma unroll
    for (int n = 0; n < 16; n++) h[n] = 0.f;
    float dsum = 0.f;
    for (int ll = 0; ll < CL; ll++) {
        float dc = dtt[ll * 256 + tid];
        float xc = xsh[ll * 256 + tid];
        float du = dc * xc;
#pragma unroll
        for (int q = 0; q < 4; q++) {
            float4 v = *(const float4*)&bsm[ll * NST + q * 4];   // broadcast
            h[q * 4 + 0] = fmaf(__expf(dc * A[q * 4 + 0]), h[q * 4 + 0], du * v.x);
            h[q * 4 + 1] = fmaf(__expf(dc * A[q * 4 + 1]), h[q * 4 + 1], du * v.y);
            h[q * 4 + 2] = fmaf(__expf(dc * A[q * 4 + 2]), h[q * 4 + 2], du * v.z);
            h[q * 4 + 3] = fmaf(__expf(dc * A[q * 4 + 3]), h[q * 4 + 3], du * v.w);
        }
        dsum += dc;
    }
    const long cb = ((long)(b * NCH + c) * DI + d);
#pragma unroll
    for (int q = 0; q < 4; q++)
        *(float4*)&hloc[cb * 16 + q * 4] =
            make_float4(h[q * 4], h[q * 4 + 1], h[q * 4 + 2], h[q * 4 + 3]);
    dsumb[cb] = dsum;
}

// ===== S2: prefix over chunks -> separate entry buffer (loads all hoistable) =====
__global__ __launch_bounds__(256, 1) void scan_prefix(const float* __restrict__ A_log,
                                                      const float* __restrict__ hloc,
                                                      const float* __restrict__ dsumb,
                                                      float* __restrict__ hent) {
    const int g = blockIdx.x * 256 + threadIdx.x;   // 65536 threads
    const int n = g & 15;
    const int d = (g >> 4) & (DI - 1);
    const int b = g >> 15;
    const float An = -__expf(A_log[(long)d * NST + n]);
    const long hstr = (long)DI * NST;
    const long hbase = (long)b * NCH * hstr + (long)d * NST + n;
    const long dbase = (long)b * NCH * DI + d;
    // load everything up-front: 1 block/CU -> huge VGPR headroom, deep MLP
    float hl[NCH], dsv[NCH];
#pragma unroll
    for (int cc = 0; cc < NCH; cc++) {
        hl[cc] = hloc[hbase + cc * hstr];
        dsv[cc] = dsumb[dbase + cc * DI];
    }
    float e[NCH];
#pragma unroll
    for (int cc = 0; cc < NCH; cc++) e[cc] = __expf(An * dsv[cc]);
    float hc = 0.f;
#pragma unroll
    for (int cc = 0; cc < NCH; cc++) {
        hent[hbase + cc * hstr] = hc;              // entry state of chunk cc
        hc = fmaf(e[cc], hc, hl[cc]);              // state at end of chunk cc
    }
}

// ===== S3: output pass — x/delta tiles staged via global_load_lds =====
__global__ __launch_bounds__(256, 2) void scan_out(const float* __restrict__ x,
                                                   const float* __restrict__ xdbl,
                                                   const float* __restrict__ A_log,
                                                   const float* __restrict__ Dp,
                                                   const float* __restrict__ hent,
                                                   float* __restrict__ out) {
    __shared__ float xsh[CL * 256];   // 32 KB
    __shared__ float dsh[CL * 256];   // 32 KB (delta, currently in `out`)
    __shared__ float bsm[CL * NST];
    __shared__ float csm[CL * NST];
    const int tid = threadIdx.x;
    const int d0 = blockIdx.x * 256;
    const int c = blockIdx.y;
    const int b = blockIdx.z;
    const int row0 = b * L_SEQ + c * CL;
    const int wv = tid >> 6, ln = tid & 63;

#pragma unroll
    for (int r8 = 0; r8 < 8; r8++) {
        int r = wv * 8 + r8;                        // wave-uniform
        glds16(&x[(long)(row0 + r) * DI + d0 + ln * 4], &xsh[r * 256]);
        glds16(&out[(long)(row0 + r) * DI + d0 + ln * 4], &dsh[r * 256]);
    }
    {
        int i = tid & 127, r = i >> 2, q = i & 3;
        float4 v = *(const float4*)&xdbl[(long)(row0 + r) * E_DIM + 64 + ((tid >> 7) << 4) + q * 4];
        if (tid < 128) ((float4*)bsm)[i] = v;
        else           ((float4*)csm)[i] = v;
    }

    const int d = d0 + tid;
    float A[16];
#pragma unroll
    for (int q = 0; q < 4; q++) {
        float4 v = *(const float4*)&A_log[(long)d * NST + q * 4];
        A[q * 4 + 0] = -__expf(v.x);
        A[q * 4 + 1] = -__expf(v.y);
        A[q * 4 + 2] = -__expf(v.z);
        A[q * 4 + 3] = -__expf(v.w);
    }
    float h[16];
    const long cb = ((long)(b * NCH + c) * DI + d);
#pragma unroll
    for (int q = 0; q < 4; q++) {
        float4 v = *(const float4*)&hent[cb * 16 + q * 4];
        h[q * 4 + 0] = v.x; h[q * 4 + 1] = v.y; h[q * 4 + 2] = v.z; h[q * 4 + 3] = v.w;
    }
    const float Dd = Dp[d];
    __syncthreads();   // drains glds (vmcnt) + bsm/csm stores

    long idx = (long)row0 * DI + d;
    for (int ll = 0; ll < CL; ll++) {
        float dc = dsh[ll * 256 + tid];
        float xc = xsh[ll * 256 + tid];
        float du = dc * xc;
        float y = 0.f;
#pragma unroll
        for (int q = 0; q < 4; q++) {
            float4 v = *(const float4*)&bsm[ll * NST + q * 4];
            float4 w = *(const float4*)&csm[ll * NST + q * 4];
            float e0 = __expf(dc * A[q * 4 + 0]);
            float e1 = __expf(dc * A[q * 4 + 1]);
            float e2 = __expf(dc * A[q * 4 + 2]);
            float e3 = __expf(dc * A[q * 4 + 3]);
            h[q * 4 + 0] = fmaf(e0, h[q * 4 + 0], du * v.x);
            h[q * 4 + 1] = fmaf(e1, h[q * 4 + 1], du * v.y);
            h[q * 4 + 2] = fmaf(e2, h[q * 4 + 2], du * v.z);
            h[q * 4 + 3] = fmaf(e3, h[q * 4 + 3], du * v.w);
            y = fmaf(h[q * 4 + 0], w.x, y);
            y = fmaf(h[q * 4 + 1], w.y, y);
            y = fmaf(h[q * 4 + 2], w.z, y);
            y = fmaf(h[q * 4 + 3], w.w, y);
        }
        out[idx] = fmaf(xc, Dd, y);
        idx += DI;
    }
}

extern "C" void kernel_launch(void* const* d_in, const int* in_sizes, int n_in,
                              void* d_out, int out_size, void* d_ws, size_t ws_size,
                              hipStream_t stream) {
    const float* x    = (const float*)d_in[0];
    const float* Wx   = (const float*)d_in[1];
    const float* Wdt  = (const float*)d_in[2];
    const float* bdt  = (const float*)d_in[3];
    const float* Alog = (const float*)d_in[4];
    const float* Dp   = (const float*)d_in[5];
    float* out = (float*)d_out;
    float* ws = (float*)d_ws;
    float* xdbl  = ws + WS_XDBL;
    float* partb = ws + WS_PART;
    float* hloc  = ws + WS_HLOC;   // overlays partb (disjoint lifetime)
    float* dsumb = ws + WS_DSUM;
    float* hent  = ws + WS_HENT;

    gemm_xproj_part<<<dim3(NROW / 64, SPLITK), 256, 0, stream>>>(x, Wx, partb);
    xproj_reduce<<<dim3(NROW * E_DIM / 4 / 256), 256, 0, stream>>>(partb, xdbl);
    gemm_dt_scan<<<dim3(DI / 256, NCH, BATCH), 256, 0, stream>>>(x, xdbl, Wdt, bdt, Alog,
                                                                 out, hloc, dsumb);
    scan_prefix<<<dim3(BATCH * DI * NST / 256), 256, 0, stream>>>(Alog, hloc, dsumb, hent);
    scan_out<<<dim3(DI / 256, NCH, BATCH), 256, 0, stream>>>(x, xdbl, Alog, Dp, hent, out);
}

// Round 2
// 201.988 us; speedup vs baseline: 1.0290x; 1.0290x over previous
//
#include <hip/hip_runtime.h>

#define BATCH 2
#define L_SEQ 2048
#define DI 2048
#define NROW (BATCH * L_SEQ)   // 4096
#define E_DIM 96
#define RNK 64                 // DT_RANK
#define NST 16                 // D_STATE
#define NCH 64                 // chunks
#define CL 32                  // chunk length (NCH*CL == L_SEQ)
#define SPLITK 16              // K1 split-K factor
#define KSL (DI / SPLITK)      // 128 k per split

// ---------------- workspace layout (floats) ----------------
// xdbl  : [NROW][96]                              393216
// partials : [SPLITK][NROW][96]   6291456  (K1 -> reduce, then dead)
//   hloc   : [BATCH][NCH][DI][16] 4194304  (overlays partials; C -> S2)
//   dsum   : [BATCH][NCH][DI]      262144  (overlays partials; C -> S2)
// hent  : [BATCH][NCH][DI][16]    4194304  (S2 -> S3), after partials
#define WS_XDBL 0
#define WS_PART 393216
#define WS_HLOC 393216
#define WS_DSUM (393216 + 4194304)
#define WS_HENT (393216 + 6291456)

__device__ __forceinline__ float softplusf(float z) {
    return fmaxf(z, 0.f) + __logf(1.f + __expf(-fabsf(z)));
}

// raw barrier: LDS-visibility only (lgkmcnt), does NOT drain vmcnt.
// Keeps register prefetches / fire-and-forget stores in flight.
__device__ __forceinline__ void barrier_lds() {
    asm volatile("s_waitcnt lgkmcnt(0)" ::: "memory");
    __builtin_amdgcn_s_barrier();
}

// ===== K1a: partial[s] = x[:, ksl] @ W^T slice =====
// 256 threads, tile M=64 x N=96, k-step 32, KSL=128. grid (64, 16).
__global__ __launch_bounds__(256) void gemm_xproj_part(const float* __restrict__ x,
                                                       const float* __restrict__ Wx,
                                                       float* __restrict__ part) {
    __shared__ float xs[32][68];    // [k][row], pitch 272B (16B aligned)
    __shared__ float wsh[32][100];  // [k][e],  pitch 400B (16B aligned)
    const int tid = threadIdx.x;
    const int r0 = blockIdx.x * 64;
    const int kbase0 = blockIdx.y * KSL;
    const int rg = tid >> 4;   // 16 groups of 4 rows
    const int cg = tid & 15;   // 16 groups of 6 cols

    float acc[4][6];
#pragma unroll
    for (int i = 0; i < 4; i++)
#pragma unroll
        for (int j = 0; j < 6; j++) acc[i][j] = 0.f;

    for (int kt = 0; kt < KSL / 32; kt++) {
        const int kb = kbase0 + kt * 32;
#pragma unroll
        for (int rep = 0; rep < 2; rep++) {
            int i = rep * 256 + tid;   // 0..511
            int row = i >> 3;          // 0..63
            int kq = i & 7;
            float4 v = *(const float4*)&x[(long)(r0 + row) * DI + kb + kq * 4];
            xs[kq * 4 + 0][row] = v.x;
            xs[kq * 4 + 1][row] = v.y;
            xs[kq * 4 + 2][row] = v.z;
            xs[kq * 4 + 3][row] = v.w;
        }
#pragma unroll
        for (int rep = 0; rep < 3; rep++) {
            int i = rep * 256 + tid;   // 0..767
            int e = i >> 3;            // 0..95
            int kq = i & 7;
            float4 v = *(const float4*)&Wx[(long)e * DI + kb + kq * 4];
            wsh[kq * 4 + 0][e] = v.x;
            wsh[kq * 4 + 1][e] = v.y;
            wsh[kq * 4 + 2][e] = v.z;
            wsh[kq * 4 + 3][e] = v.w;
        }
        __syncthreads();
#pragma unroll 8
        for (int k = 0; k < 32; k++) {
            float xr[4], wr[6];
#pragma unroll
            for (int i = 0; i < 4; i++) xr[i] = xs[k][rg * 4 + i];
#pragma unroll
            for (int j = 0; j < 6; j++) wr[j] = wsh[k][cg * 6 + j];
#pragma unroll
            for (int i = 0; i < 4; i++)
#pragma unroll
                for (int j = 0; j < 6; j++) acc[i][j] = fmaf(xr[i], wr[j], acc[i][j]);
        }
        __syncthreads();
    }
    const long sbase = (long)blockIdx.y * NROW * E_DIM;
#pragma unroll
    for (int i = 0; i < 4; i++) {
        long rowb = sbase + (long)(r0 + rg * 4 + i) * E_DIM + cg * 6;
#pragma unroll
        for (int j = 0; j < 6; j++) part[rowb + j] = acc[i][j];
    }
}

// ===== K1b: xdbl = sum over splits (float4-vectorized) =====
__global__ __launch_bounds__(256) void xproj_reduce(const float* __restrict__ part,
                                                    float* __restrict__ xdbl) {
    const int i4 = blockIdx.x * 256 + threadIdx.x;   // 98304 float4 outputs
    const float4* p4 = (const float4*)part;
    float4 s = p4[i4];
#pragma unroll
    for (int sp = 1; sp < SPLITK; sp++) {
        float4 v = p4[(long)sp * (NROW * E_DIM / 4) + i4];
        s.x += v.x; s.y += v.y; s.z += v.z; s.w += v.w;
    }
    ((float4*)xdbl)[i4] = s;
}

// ===== C: fused delta-GEMM + chunk-local scan =====
// grid (DI/256, NCH, BATCH), 256 threads. Per block: 32 l (one chunk) x 256 d.
// x column prefetched to REGISTERS (issued after kt=0 staging loads, lands
// under the GEMM); raw barriers (lgkmcnt-only) never drain vmcnt.
#define PW 260   // wt pitch (floats), 1040B rows (16B aligned)
#define PD 36    // dlb pitch (floats), 144B rows (16B aligned)
__global__ __launch_bounds__(256) void gemm_dt_scan(const float* __restrict__ x,
                                                    const float* __restrict__ xdbl,
                                                    const float* __restrict__ Wdt,
                                                    const float* __restrict__ b_dt,
                                                    const float* __restrict__ A_log,
                                                    float* __restrict__ delta,
                                                    float* __restrict__ hloc,
                                                    float* __restrict__ dsumb) {
    __shared__ float region[32 * PW + 32 * PD];   // GEMM staging; dtt overlay (~37.9 KB)
    __shared__ float bsm[CL * NST];               // 2 KB B tile
    float* wt  = region;                 // [32][PW]  Wdt staging [k][col]
    float* dlb = region + 32 * PW;       // [32][PD]  dlt staging [k][row]
    float* dtt = region;                 // [32][256] delta tile (overlay, after GEMM)

    const int tid = threadIdx.x;
    const int d0 = blockIdx.x * 256;
    const int c = blockIdx.y;
    const int b = blockIdx.z;
    const int row0 = b * L_SEQ + c * CL;
    const int d = d0 + tid;
    const int rg = tid >> 6;   // 4 groups of 8 rows (wave-uniform)
    const int cg = tid & 63;   // 64 groups of 4 cols

    // B tile (rows row0..row0+31, xdbl cols 64..79)
    if (tid < 128) {
        int r = tid >> 2, q = tid & 3;
        ((float4*)bsm)[tid] = *(const float4*)&xdbl[(long)(row0 + r) * E_DIM + 64 + q * 4];
    }

    float acc[8][4];
#pragma unroll
    for (int i = 0; i < 8; i++)
#pragma unroll
        for (int j = 0; j < 4; j++) acc[i][j] = 0.f;

    float xv[CL];     // x column prefetch (registers)
    float4 av[4];     // raw A_log (exp applied later)

#pragma unroll
    for (int kt = 0; kt < 2; kt++) {
        const int kb = kt * 32;
        // Wdt tile: 256 cols x 32 k = 2048 float4, 8/thread
#pragma unroll
        for (int rep = 0; rep < 8; rep++) {
            int i = rep * 256 + tid;
            int col = i >> 3, kq = i & 7;
            float4 v = *(const float4*)&Wdt[(long)(d0 + col) * RNK + kb + kq * 4];
            wt[(kq * 4 + 0) * PW + col] = v.x;
            wt[(kq * 4 + 1) * PW + col] = v.y;
            wt[(kq * 4 + 2) * PW + col] = v.z;
            wt[(kq * 4 + 3) * PW + col] = v.w;
        }
        // dlt tile: 32 rows x 32 k = 256 float4, 1/thread
        {
            int r = tid >> 3, kq = tid & 7;
            float4 v = *(const float4*)&xdbl[(long)(row0 + r) * E_DIM + kb + kq * 4];
            dlb[(kq * 4 + 0) * PD + r] = v.x;
            dlb[(kq * 4 + 1) * PD + r] = v.y;
            dlb[(kq * 4 + 2) * PD + r] = v.z;
            dlb[(kq * 4 + 3) * PD + r] = v.w;
        }
        if (kt == 0) {
            // issue x + A prefetch AFTER staging loads: staging's vmcnt waits
            // (FIFO, staging older) don't force these; they land under GEMM kt0/kt1.
#pragma unroll
            for (int ll = 0; ll < CL; ll++)
                xv[ll] = x[(long)(row0 + ll) * DI + d];
#pragma unroll
            for (int q = 0; q < 4; q++)
                av[q] = *(const float4*)&A_log[(long)d * NST + q * 4];
        }
        barrier_lds();
#pragma unroll 8
        for (int k = 0; k < 32; k++) {
            float4 xa = *(const float4*)&dlb[k * PD + rg * 8];       // broadcast
            float4 xb = *(const float4*)&dlb[k * PD + rg * 8 + 4];   // broadcast
            float4 wv4 = *(const float4*)&wt[k * PW + cg * 4];       // 16B-stride
            float xr[8] = {xa.x, xa.y, xa.z, xa.w, xb.x, xb.y, xb.z, xb.w};
            float wr[4] = {wv4.x, wv4.y, wv4.z, wv4.w};
#pragma unroll
            for (int i = 0; i < 8; i++)
#pragma unroll
                for (int j = 0; j < 4; j++) acc[i][j] = fmaf(xr[i], wr[j], acc[i][j]);
        }
        barrier_lds();   // protects staging overwrite (kt=1) / dtt overlay (epilogue)
    }

    // epilogue: bias + softplus -> global delta (fire-and-forget) + LDS delta tile
    float4 bb = *(const float4*)&b_dt[d0 + cg * 4];
#pragma unroll
    for (int i = 0; i < 8; i++) {
        int r = rg * 8 + i;
        float4 o;
        o.x = softplusf(acc[i][0] + bb.x);
        o.y = softplusf(acc[i][1] + bb.y);
        o.z = softplusf(acc[i][2] + bb.z);
        o.w = softplusf(acc[i][3] + bb.w);
        *(float4*)&delta[(long)(row0 + r) * DI + d0 + cg * 4] = o;
        *(float4*)&dtt[r * 256 + cg * 4] = o;
    }

    float A[16];
#pragma unroll
    for (int q = 0; q < 4; q++) {
        A[q * 4 + 0] = -__expf(av[q].x);
        A[q * 4 + 1] = -__expf(av[q].y);
        A[q * 4 + 2] = -__expf(av[q].z);
        A[q * 4 + 3] = -__expf(av[q].w);
    }
    barrier_lds();   // dtt visible; delta stores + nothing else forced

    float h[16];
#pragma unroll
    for (int n = 0; n < 16; n++) h[n] = 0.f;
    float dsum = 0.f;
    for (int ll = 0; ll < CL; ll++) {
        float dc = dtt[ll * 256 + tid];
        float du = dc * xv[ll];
#pragma unroll
        for (int q = 0; q < 4; q++) {
            float4 v = *(const float4*)&bsm[ll * NST + q * 4];   // broadcast
            h[q * 4 + 0] = fmaf(__expf(dc * A[q * 4 + 0]), h[q * 4 + 0], du * v.x);
            h[q * 4 + 1] = fmaf(__expf(dc * A[q * 4 + 1]), h[q * 4 + 1], du * v.y);
            h[q * 4 + 2] = fmaf(__expf(dc * A[q * 4 + 2]), h[q * 4 + 2], du * v.z);
            h[q * 4 + 3] = fmaf(__expf(dc * A[q * 4 + 3]), h[q * 4 + 3], du * v.w);
        }
        dsum += dc;
    }
    const long cb = ((long)(b * NCH + c) * DI + d);
#pragma unroll
    for (int q = 0; q < 4; q++)
        *(float4*)&hloc[cb * 16 + q * 4] =
            make_float4(h[q * 4], h[q * 4 + 1], h[q * 4 + 2], h[q * 4 + 3]);
    dsumb[cb] = dsum;
}

// ===== S2: prefix over chunks -> separate entry buffer (loads all hoistable) =====
__global__ __launch_bounds__(256, 1) void scan_prefix(const float* __restrict__ A_log,
                                                      const float* __restrict__ hloc,
                                                      const float* __restrict__ dsumb,
                                                      float* __restrict__ hent) {
    const int g = blockIdx.x * 256 + threadIdx.x;   // 65536 threads
    const int n = g & 15;
    const int d = (g >> 4) & (DI - 1);
    const int b = g >> 15;
    const float An = -__expf(A_log[(long)d * NST + n]);
    const long hstr = (long)DI * NST;
    const long hbase = (long)b * NCH * hstr + (long)d * NST + n;
    const long dbase = (long)b * NCH * DI + d;
    float hl[NCH], dsv[NCH];
#pragma unroll
    for (int cc = 0; cc < NCH; cc++) {
        hl[cc] = hloc[hbase + cc * hstr];
        dsv[cc] = dsumb[dbase + cc * DI];
    }
    float e[NCH];
#pragma unroll
    for (int cc = 0; cc < NCH; cc++) e[cc] = __expf(An * dsv[cc]);
    float hc = 0.f;
#pragma unroll
    for (int cc = 0; cc < NCH; cc++) {
        hent[hbase + cc * hstr] = hc;              // entry state of chunk cc
        hc = fmaf(e[cc], hc, hl[cc]);              // state at end of chunk cc
    }
}

// ===== S3: output pass — x/delta columns prefetched to REGISTERS =====
// Params (A, hent, Dp) issued FIRST so their waitcnt doesn't drain the
// column loads; 64 outstanding dword loads/thread give the MLP to hit BW.
__global__ __launch_bounds__(256) void scan_out(const float* __restrict__ x,
                                                const float* __restrict__ xdbl,
                                                const float* __restrict__ A_log,
                                                const float* __restrict__ Dp,
                                                const float* __restrict__ hent,
                                                float* __restrict__ out) {
    __shared__ float bsm[CL * NST];
    __shared__ float csm[CL * NST];
    const int tid = threadIdx.x;
    const int d0 = blockIdx.x * 256;
    const int c = blockIdx.y;
    const int b = blockIdx.z;
    const int row0 = b * L_SEQ + c * CL;
    const int d = d0 + tid;

    {
        int i = tid & 127, r = i >> 2, q = i & 3;
        float4 v = *(const float4*)&xdbl[(long)(row0 + r) * E_DIM + 64 + ((tid >> 7) << 4) + q * 4];
        if (tid < 128) ((float4*)bsm)[i] = v;
        else           ((float4*)csm)[i] = v;
    }
    __syncthreads();   // only LDS staging outstanding; cheap drain

    // params first (oldest in vmcnt FIFO)
    float4 av[4];
#pragma unroll
    for (int q = 0; q < 4; q++)
        av[q] = *(const float4*)&A_log[(long)d * NST + q * 4];
    const long cb = ((long)(b * NCH + c) * DI + d);
    float4 hv[4];
#pragma unroll
    for (int q = 0; q < 4; q++)
        hv[q] = *(const float4*)&hent[cb * 16 + q * 4];
    const float Dd = Dp[d];

    // column prefetch: delta (in `out`) + x, interleaved in use-order
    float dv[CL], xv[CL];
#pragma unroll
    for (int ll = 0; ll < CL; ll++) {
        dv[ll] = out[(long)(row0 + ll) * DI + d];
        xv[ll] = x[(long)(row0 + ll) * DI + d];
    }

    float A[16];
#pragma unroll
    for (int q = 0; q < 4; q++) {
        A[q * 4 + 0] = -__expf(av[q].x);
        A[q * 4 + 1] = -__expf(av[q].y);
        A[q * 4 + 2] = -__expf(av[q].z);
        A[q * 4 + 3] = -__expf(av[q].w);
    }
    float h[16];
#pragma unroll
    for (int q = 0; q < 4; q++) {
        h[q * 4 + 0] = hv[q].x; h[q * 4 + 1] = hv[q].y;
        h[q * 4 + 2] = hv[q].z; h[q * 4 + 3] = hv[q].w;
    }

    long idx = (long)row0 * DI + d;
    for (int ll = 0; ll < CL; ll++) {
        float dc = dv[ll];
        float xc = xv[ll];
        float du = dc * xc;
        float y = 0.f;
#pragma unroll
        for (int q = 0; q < 4; q++) {
            float4 v = *(const float4*)&bsm[ll * NST + q * 4];
            float4 w = *(const float4*)&csm[ll * NST + q * 4];
            float e0 = __expf(dc * A[q * 4 + 0]);
            float e1 = __expf(dc * A[q * 4 + 1]);
            float e2 = __expf(dc * A[q * 4 + 2]);
            float e3 = __expf(dc * A[q * 4 + 3]);
            h[q * 4 + 0] = fmaf(e0, h[q * 4 + 0], du * v.x);
            h[q * 4 + 1] = fmaf(e1, h[q * 4 + 1], du * v.y);
            h[q * 4 + 2] = fmaf(e2, h[q * 4 + 2], du * v.z);
            h[q * 4 + 3] = fmaf(e3, h[q * 4 + 3], du * v.w);
            y = fmaf(h[q * 4 + 0], w.x, y);
            y = fmaf(h[q * 4 + 1], w.y, y);
            y = fmaf(h[q * 4 + 2], w.z, y);
            y = fmaf(h[q * 4 + 3], w.w, y);
        }
        out[idx] = fmaf(xc, Dd, y);
        idx += DI;
    }
}

extern "C" void kernel_launch(void* const* d_in, const int* in_sizes, int n_in,
                              void* d_out, int out_size, void* d_ws, size_t ws_size,
                              hipStream_t stream) {
    const float* x    = (const float*)d_in[0];
    const float* Wx   = (const float*)d_in[1];
    const float* Wdt  = (const float*)d_in[2];
    const float* bdt  = (const float*)d_in[3];
    const float* Alog = (const float*)d_in[4];
    const float* Dp   = (const float*)d_in[5];
    float* out = (float*)d_out;
    float* ws = (float*)d_ws;
    float* xdbl  = ws + WS_XDBL;
    float* partb = ws + WS_PART;
    float* hloc  = ws + WS_HLOC;   // overlays partb (disjoint lifetime)
    float* dsumb = ws + WS_DSUM;
    float* hent  = ws + WS_HENT;

    gemm_xproj_part<<<dim3(NROW / 64, SPLITK), 256, 0, stream>>>(x, Wx, partb);
    xproj_reduce<<<dim3(NROW * E_DIM / 4 / 256), 256, 0, stream>>>(partb, xdbl);
    gemm_dt_scan<<<dim3(DI / 256, NCH, BATCH), 256, 0, stream>>>(x, xdbl, Wdt, bdt, Alog,
                                                                 out, hloc, dsumb);
    scan_prefix<<<dim3(BATCH * DI * NST / 256), 256, 0, stream>>>(Alog, hloc, dsumb, hent);
    scan_out<<<dim3(DI / 256, NCH, BATCH), 256, 0, stream>>>(x, xdbl, Alog, Dp, hent, out);
}